// Round 17
// baseline (208.247 us; speedup 1.0000x reference)
//
#include <hip/hip_runtime.h>
#include <hip/hip_bf16.h>

// B=4, T=2048, D=1024, H=16, HD=64
#define Bsz 4
#define Tsz 2048
#define Dsz 1024
#define Hsz 16
#define HDsz 64

typedef __attribute__((ext_vector_type(8))) __bf16 bf16x8;
typedef __attribute__((ext_vector_type(4))) __bf16 bf16x4;
typedef __attribute__((ext_vector_type(4))) float f32x4;
typedef __attribute__((ext_vector_type(2))) float f32x2;
typedef unsigned short u16;
typedef unsigned int u32;

#define DEVI static __device__ __forceinline__

DEVI u16 f2bf(float f) {
    __bf16 h = (__bf16)f;
    union { __bf16 h; u16 u; } c; c.h = h; return c.u;
}
DEVI bf16x8 ld_bf8(const u16* p) { return *reinterpret_cast<const bf16x8*>(p); }

// async global->LDS, 16B per lane. lds dest is wave-uniform base + lane*16.
DEVI void gll16(const u16* g, u16* lds) {
    __builtin_amdgcn_global_load_lds(
        (const __attribute__((address_space(1))) u32*)g,
        (__attribute__((address_space(3))) u32*)lds, 16, 0, 0);
}

// K=16 MFMA: acc(16x16, f32) += A(16x16 bf16) * B(16x16 bf16).
DEVI void mfma16(f32x4& c, f32x2 a, f32x2 b) {
    asm("v_mfma_f32_16x16x16_bf16 %0, %1, %2, %0" : "+v"(c) : "v"(a), "v"(b));
}

// ---------------------------------------------------------------------------
// fp32 -> bf16 bulk convert (8 elems/thread, single pass)
// ---------------------------------------------------------------------------
__global__ __launch_bounds__(256)
void conv_bf16(const float* __restrict__ X, u16* __restrict__ Xb)
{
    const size_t i = ((size_t)blockIdx.x * 256 + threadIdx.x) * 8;
    const float4 a = *(const float4*)(X + i);
    const float4 b = *(const float4*)(X + i + 4);
    u16 h[8] = { f2bf(a.x), f2bf(a.y), f2bf(a.z), f2bf(a.w),
                 f2bf(b.x), f2bf(b.y), f2bf(b.z), f2bf(b.w) };
    *(uint4*)(Xb + i) = *(uint4*)h;
}

// ---------------------------------------------------------------------------
// Transpose+convert: W[K][N] fp32 -> WT[N][K] bf16. 64x64 tiles.
// ---------------------------------------------------------------------------
__global__ __launch_bounds__(256)
void transpose_w(const float* __restrict__ W, u16* __restrict__ WT, int K, int N)
{
    __shared__ float tile[64][65];
    const int n0 = blockIdx.x * 64, k0 = blockIdx.y * 64;
    const int t = threadIdx.x;
    #pragma unroll
    for (int i = 0; i < 4; ++i) {
        const int idx = i*256 + t;
        const int row = idx >> 4, c4 = (idx & 15) * 4;
        const float4 v = *(const float4*)(W + (size_t)(k0 + row)*N + n0 + c4);
        tile[row][c4+0] = v.x; tile[row][c4+1] = v.y;
        tile[row][c4+2] = v.z; tile[row][c4+3] = v.w;
    }
    __syncthreads();
    #pragma unroll
    for (int j = 0; j < 2; ++j) {
        const int idx = j*256 + t;
        const int nr = idx >> 3, kc = (idx & 7) * 8;
        u16 h[8];
        #pragma unroll
        for (int e = 0; e < 8; ++e) h[e] = f2bf(tile[kc + e][nr]);
        *(uint4*)(WT + (size_t)(n0 + nr)*K + k0 + kc) = *(uint4*)h;
    }
}

// ---------------------------------------------------------------------------
// 128x128 bf16 MFMA GEMM, BK=32. 256 threads, 4 waves (64x64 out, 4x4 frags),
// 3-stage LDS pipeline, counted s_waitcnt vmcnt(4) + raw s_barrier; final
// step drains vmcnt(0). L2-aware XCD mapping: per-XCD chunk covers only
// nx/8 B-panels (B working set fits the 4MB per-XCD L2; A-panel uses are
// back-to-back). Epilogue: branch hoisted per (i,j); V^T stores ushort4.
// LDS XOR-swizzle (chunk ^= (row>>1)&3), pre-swizzled global source.
// ---------------------------------------------------------------------------
template<int EPI>
__global__ __launch_bounds__(256, 3)
void gemm128(const u16* __restrict__ A, const u16* __restrict__ Bt,
             const float* __restrict__ bias, float* __restrict__ Cf,
             u16* __restrict__ Qo, u16* __restrict__ Ko, u16* __restrict__ Vo,
             int M, int N, int K)
{
    __shared__ u16 As[3][128][32];
    __shared__ u16 Bs[3][128][32];

    const int nx  = N >> 7;                   // 24 (QKV) or 8 (proj), % 8 == 0
    const int q   = nx >> 3;                  // B-panels per XCD chunk
    const int xcd = blockIdx.x & 7;
    const int c   = blockIdx.x >> 3;          // chunk-local index
    const int tN  = xcd * q + (q > 1 ? (c % q) : 0);
    const int tM  = (q > 1 ? (c / q) : c);

    const int t = threadIdx.x, l = t & 63, w = t >> 6;
    const int wm = w >> 1, wn = w & 1;
    const int lrow = l & 15, lk = l >> 4;

    f32x4 acc[4][4] = {};

    const u16* Ag = A  + (size_t)tM * 128 * K;
    const u16* Bg = Bt + (size_t)tN * 128 * K;

    int srow[2], sch[2];
    #pragma unroll
    for (int r = 0; r < 2; ++r) {
        const int cc = r*256 + t;
        srow[r] = cc >> 2;
        sch[r]  = (cc & 3) ^ ((srow[r] >> 1) & 3);
    }
    const size_t ldso = (size_t)(t & 192) * 8;

    #define STAGE(buf, ks)                                                      \
        {                                                                       \
            _Pragma("unroll")                                                   \
            for (int r = 0; r < 2; ++r) {                                       \
                gll16(Ag + (size_t)srow[r]*K + (ks) + sch[r]*8,                 \
                      &As[buf][0][0] + (size_t)r*2048 + ldso);                  \
                gll16(Bg + (size_t)srow[r]*K + (ks) + sch[r]*8,                 \
                      &Bs[buf][0][0] + (size_t)r*2048 + ldso);                  \
            }                                                                   \
        }

    STAGE(0, 0);
    STAGE(1, 32);

    const int nk = K >> 5;                    // 32
    int cur = 0;
    for (int i = 0; i < nk; ++i) {
        if (i + 1 < nk) { asm volatile("s_waitcnt vmcnt(4)" ::: "memory"); }
        else            { asm volatile("s_waitcnt vmcnt(0)" ::: "memory"); }
        __builtin_amdgcn_sched_barrier(0);
        __builtin_amdgcn_s_barrier();

        bf16x8 a[4], bb[4];
        #pragma unroll
        for (int ii = 0; ii < 4; ++ii) {
            const int ar = wm*64 + ii*16 + lrow;
            a[ii] = ld_bf8(&As[cur][ar][(lk ^ ((ar >> 1) & 3)) * 8]);
        }
        #pragma unroll
        for (int j = 0; j < 4; ++j) {
            const int br = wn*64 + j*16 + lrow;
            bb[j] = ld_bf8(&Bs[cur][br][(lk ^ ((br >> 1) & 3)) * 8]);
        }

        if (i + 2 < nk) {
            const int nb = (cur + 2) - ((cur + 2) >= 3 ? 3 : 0);
            STAGE(nb, (i + 2) * 32);
        }

        __builtin_amdgcn_s_setprio(1);
        #pragma unroll
        for (int ii = 0; ii < 4; ++ii)
        #pragma unroll
        for (int j = 0; j < 4; ++j)
            acc[ii][j] = __builtin_amdgcn_mfma_f32_16x16x32_bf16(a[ii], bb[j], acc[ii][j], 0, 0, 0);
        __builtin_amdgcn_s_setprio(0);

        cur = (cur + 1) - ((cur + 1) >= 3 ? 3 : 0);
    }
    #undef STAGE

    #pragma unroll
    for (int i = 0; i < 4; ++i)
    #pragma unroll
    for (int j = 0; j < 4; ++j) {
        const int row0 = tM*128 + wm*64 + i*16 + lk*4;
        const int col  = tN*128 + wn*64 + j*16 + lrow;
        const float bv = bias[col];
        if (EPI == 0) {
            #pragma unroll
            for (int r = 0; r < 4; ++r)
                Cf[(size_t)(row0 + r) * N + col] = acc[i][j][r] + bv;
        } else {
            const int which = col >> 10;
            const int h  = (col & 1023) >> 6;
            const int hd = col & 63;
            if (which == 2) {
                const int b  = row0 >> 11;
                const int tt = row0 & 2047;
                const int bh = b * Hsz + h;
                u16 pk[4] = { f2bf(acc[i][j][0] + bv), f2bf(acc[i][j][1] + bv),
                              f2bf(acc[i][j][2] + bv), f2bf(acc[i][j][3] + bv) };
                *(ushort4*)(Vo + ((size_t)bh * HDsz + hd) * Tsz + tt) = *(ushort4*)pk;
            } else {
                u16* P = (which == 0) ? Qo : Ko;
                #pragma unroll
                for (int r = 0; r < 4; ++r) {
                    const int row = row0 + r;
                    const int bh  = (row >> 11) * Hsz + h;
                    P[((size_t)bh * Tsz + (row & 2047)) * HDsz + hd] =
                        f2bf(acc[i][j][r] + bv);
                }
            }
        }
    }
}

// ---------------------------------------------------------------------------
// Flash attention v4.1 (causal) — R6/R11/R14's proven kernel; ONLY change:
// softmax exp path folded to exp2f with C = 0.125*log2(e) baked into the
// fmaf constant (removes the hidden v_mul that __expf emits per element:
// 1 fmaf + 1 v_exp instead of 1 fmaf + 1 v_mul + 1 v_exp). Defer-max
// rescale uses the same fold. Numerics identical to <1 ulp in the exponent.
// ---------------------------------------------------------------------------
__global__ __launch_bounds__(256, 4)
void attn3(const u16* __restrict__ Q, const u16* __restrict__ K,
           const u16* __restrict__ Vt, u16* __restrict__ AO)
{
    __shared__ u16 KV[2][2][64][64];   // [buf][K/V][row][col], 32 KB

    const int y = blockIdx.y;                       // bh
    const int x = blockIdx.x;                       // 0..15
    const int idx = (x + (y >> 4)) & 15;
    const int qt = (idx & 1) ? (idx >> 1) : (15 - (idx >> 1));
    const int bh = y;
    const int t = threadIdx.x, w = t >> 6, l = t & 63;
    const int lrow = l & 15, lk = l >> 4;
    const int qw = qt*128 + w*32;
    const int qwmax = qw + 31;
    const int swz = lrow & 7;
    const float C8 = 0.125f * 1.44269504f;          // 0.125 * log2(e)

    const u16* Qh = Q  + (size_t)bh * Tsz * HDsz;
    const u16* Kh = K  + (size_t)bh * Tsz * HDsz;
    const u16* Vh = Vt + (size_t)bh * HDsz * Tsz;

    bf16x8 qf[2][2];
    #pragma unroll
    for (int f = 0; f < 2; ++f)
    #pragma unroll
    for (int kh = 0; kh < 2; ++kh)
        qf[f][kh] = ld_bf8(&Qh[(size_t)(qw + f*16 + lrow)*HDsz + kh*32 + lk*8]);

    f32x4 o[2][4] = {};
    float m[2] = {-3e38f, -3e38f}, lsum[2] = {0.f, 0.f};

    const int ntile = 2*qt + 2;
    int cur = 0;

    #pragma unroll
    for (int rr = 0; rr < 2; ++rr) {
        const int c = rr*256 + t;
        const int row = c >> 3, gc = (c & 7) ^ (row & 7);
        gll16(Kh + (size_t)row*HDsz + gc*8,
              &KV[0][0][0][0] + (size_t)(rr*256 + (t & 192))*8);
        gll16(Vh + (size_t)row*Tsz + gc*8,
              &KV[0][1][0][0] + (size_t)(rr*256 + (t & 192))*8);
    }
    __syncthreads();

    for (int tk = 0; tk < ntile; ++tk) {
        if (tk + 1 < ntile) {
            const int nkv = (tk + 1) * 64;
            #pragma unroll
            for (int rr = 0; rr < 2; ++rr) {
                const int c = rr*256 + t;
                const int row = c >> 3, gc = (c & 7) ^ (row & 7);
                gll16(Kh + (size_t)(nkv + row)*HDsz + gc*8,
                      &KV[cur^1][0][0][0] + (size_t)(rr*256 + (t & 192))*8);
                gll16(Vh + (size_t)row*Tsz + nkv + gc*8,
                      &KV[cur^1][1][0][0] + (size_t)(rr*256 + (t & 192))*8);
            }
        }
        const int kv0 = tk * 64;
        if (kv0 <= qwmax) {
            const u16 (*Ks)[64] = KV[cur][0];
            const u16 (*Vs)[64] = KV[cur][1];
            const bool fullc    = (kv0 + 63 <= qwmax);
            const bool needmask = (kv0 + 63 > qw);

            f32x4 s[2][4];
            __builtin_amdgcn_s_setprio(1);
            #pragma unroll
            for (int c = 0; c < 4; ++c) {
                if (c >= 2 && !fullc) continue;
                const bf16x8 k0 = ld_bf8(&Ks[c*16 + lrow][((0 + lk) ^ swz) * 8]);
                const bf16x8 k1 = ld_bf8(&Ks[c*16 + lrow][((4 + lk) ^ swz) * 8]);
                #pragma unroll
                for (int f = 0; f < 2; ++f) {
                    f32x4 z = {};
                    z = __builtin_amdgcn_mfma_f32_16x16x32_bf16(k0, qf[f][0], z, 0, 0, 0);
                    z = __builtin_amdgcn_mfma_f32_16x16x32_bf16(k1, qf[f][1], z, 0, 0, 0);
                    s[f][c] = z;
                }
            }
            __builtin_amdgcn_s_setprio(0);

            #pragma unroll
            for (int f = 0; f < 2; ++f) {
                const int q = qw + f*16 + lrow;
                if (needmask) {
                    #pragma unroll
                    for (int c = 0; c < 4; ++c) {
                        if (c >= 2 && !fullc) continue;
                        const int base = kv0 + c*16 + lk*4;
                        #pragma unroll
                        for (int r = 0; r < 4; ++r)
                            if (base + r > q) s[f][c][r] = -1e30f;
                    }
                }
                f32x4 t01;
                #pragma unroll
                for (int r = 0; r < 4; ++r) {
                    t01[r] = fmaxf(s[f][0][r], s[f][1][r]);
                    if (fullc) t01[r] = fmaxf(t01[r], fmaxf(s[f][2][r], s[f][3][r]));
                }
                float mx = fmaxf(fmaxf(t01[0], t01[1]), fmaxf(t01[2], t01[3]));
                mx = fmaxf(mx, __shfl_xor(mx, 16));
                mx = fmaxf(mx, __shfl_xor(mx, 32));
                if (__any(mx > m[f] + 64.f)) {          // defer-max (THR=8 scaled)
                    const float mn = fmaxf(m[f], mx);
                    const float al = exp2f((m[f] - mn) * C8);
                    lsum[f] *= al;
                    m[f] = mn;
                    #pragma unroll
                    for (int c = 0; c < 4; ++c)
                    #pragma unroll
                    for (int r = 0; r < 4; ++r) o[f][c][r] *= al;
                }
                const float nm8 = -m[f] * C8;
                f32x4 ps4 = {};
                #pragma unroll
                for (int c = 0; c < 4; ++c) {
                    if (c >= 2 && !fullc) continue;
                    #pragma unroll
                    for (int r = 0; r < 4; ++r) {
                        const float p = exp2f(fmaf(s[f][c][r], C8, nm8));
                        s[f][c][r] = p;
                        ps4[r] += p;
                    }
                }
                float ps = (ps4[0] + ps4[1]) + (ps4[2] + ps4[3]);
                ps += __shfl_xor(ps, 16);
                ps += __shfl_xor(ps, 32);
                lsum[f] += ps;
            }

            __builtin_amdgcn_s_setprio(1);
            #pragma unroll
            for (int c = 0; c < 4; ++c) {
                if (c >= 2 && !fullc) continue;
                union { bf16x4 v; f32x2 f; } p0, p1;
                #pragma unroll
                for (int r = 0; r < 4; ++r) {
                    p0.v[r] = (__bf16)s[0][c][r];
                    p1.v[r] = (__bf16)s[1][c][r];
                }
                #pragma unroll
                for (int chd = 0; chd < 4; ++chd) {
                    const f32x2 va = *reinterpret_cast<const f32x2*>(
                        &Vs[chd*16 + lrow][(((c*2 + (lk >> 1)) ^ swz) << 3) + ((lk & 1) << 2)]);
                    mfma16(o[0][chd], va, p0.f);
                    mfma16(o[1][chd], va, p1.f);
                }
            }
            __builtin_amdgcn_s_setprio(0);
        }
        __syncthreads();
        cur ^= 1;
    }

    const int b = bh >> 4, h = bh & 15;
    #pragma unroll
    for (int f = 0; f < 2; ++f) {
        const float rl = 1.0f / lsum[f];
        #pragma unroll
        for (int chd = 0; chd < 4; ++chd) {
            u16 ov[4] = { f2bf(o[f][chd][0]*rl), f2bf(o[f][chd][1]*rl),
                          f2bf(o[f][chd][2]*rl), f2bf(o[f][chd][3]*rl) };
            *(ushort4*)(AO + ((size_t)(b*Tsz + qw + f*16 + lrow))*Dsz
                           + h*HDsz + chd*16 + lk*4) = *(ushort4*)ov;
        }
    }
}

extern "C" void kernel_launch(void* const* d_in, const int* in_sizes, int n_in,
                              void* d_out, int out_size, void* d_ws, size_t ws_size,
                              hipStream_t stream)
{
    (void)in_sizes; (void)n_in; (void)out_size; (void)ws_size;

    const float* x      = (const float*)d_in[0];
    const float* qkv_w  = (const float*)d_in[1];
    const float* qkv_b  = (const float*)d_in[2];
    const float* proj_w = (const float*)d_in[3];
    const float* proj_b = (const float*)d_in[4];
    float* out = (float*)d_out;

    char* ws = (char*)d_ws;
    const size_t SZ = (size_t)Bsz * Hsz * Tsz * HDsz * sizeof(u16);  // 16 MB
    u16* R0 = (u16*)(ws);
    u16* Qb = (u16*)(ws + SZ);
    u16* Kb = (u16*)(ws + 2*SZ);
    u16* Vt = (u16*)(ws + 3*SZ);
    u16* WQKVT = R0;          // dead after QKV GEMM
    u16* AO    = R0;          // reuses WQKVT region
    u16* WPT   = Qb;          // reuses Q region after attention

    // x as bf16, staged in d_out's first 16.8 MB (out is 33.5 MB fp32,
    // fully overwritten by the proj GEMM at the end -> safe scratch).
    u16* Xb = (u16*)d_out;

    const int M = Bsz * Tsz;  // 8192

    conv_bf16<<<(M*Dsz)/(256*8), 256, 0, stream>>>(x, Xb);
    transpose_w<<<dim3(3*Dsz/64, Dsz/64), 256, 0, stream>>>(qkv_w, WQKVT, Dsz, 3*Dsz);
    gemm128<1><<<dim3((3*Dsz/128) * (M/128)), 256, 0, stream>>>(
        Xb, WQKVT, qkv_b, nullptr, Qb, Kb, Vt, M, 3*Dsz, Dsz);
    attn3<<<dim3(Tsz/128, Bsz*Hsz), 256, 0, stream>>>(Qb, Kb, Vt, AO);
    transpose_w<<<dim3(Dsz/64, Dsz/64), 256, 0, stream>>>(proj_w, WPT, Dsz, Dsz);
    gemm128<0><<<dim3((Dsz/128) * (M/128)), 256, 0, stream>>>(
        AO, WPT, proj_b, out, nullptr, nullptr, nullptr, M, Dsz, Dsz);
}

// Round 18
// 194.546 us; speedup vs baseline: 1.0704x; 1.0704x over previous
//
#include <hip/hip_runtime.h>
#include <hip/hip_bf16.h>

// B=4, T=2048, D=1024, H=16, HD=64
#define Bsz 4
#define Tsz 2048
#define Dsz 1024
#define Hsz 16
#define HDsz 64

typedef __attribute__((ext_vector_type(8))) __bf16 bf16x8;
typedef __attribute__((ext_vector_type(4))) __bf16 bf16x4;
typedef __attribute__((ext_vector_type(4))) float f32x4;
typedef __attribute__((ext_vector_type(2))) float f32x2;
typedef unsigned short u16;
typedef unsigned int u32;

#define DEVI static __device__ __forceinline__

DEVI u16 f2bf(float f) {
    __bf16 h = (__bf16)f;
    union { __bf16 h; u16 u; } c; c.h = h; return c.u;
}
DEVI bf16x8 ld_bf8(const u16* p) { return *reinterpret_cast<const bf16x8*>(p); }

// async global->LDS, 16B per lane. lds dest is wave-uniform base + lane*16.
DEVI void gll16(const u16* g, u16* lds) {
    __builtin_amdgcn_global_load_lds(
        (const __attribute__((address_space(1))) u32*)g,
        (__attribute__((address_space(3))) u32*)lds, 16, 0, 0);
}

// K=16 MFMA: acc(16x16, f32) += A(16x16 bf16) * B(16x16 bf16).
DEVI void mfma16(f32x4& c, f32x2 a, f32x2 b) {
    asm("v_mfma_f32_16x16x16_bf16 %0, %1, %2, %0" : "+v"(c) : "v"(a), "v"(b));
}

// ---------------------------------------------------------------------------
// fp32 -> bf16 bulk convert (8 elems/thread, single pass)
// ---------------------------------------------------------------------------
__global__ __launch_bounds__(256)
void conv_bf16(const float* __restrict__ X, u16* __restrict__ Xb)
{
    const size_t i = ((size_t)blockIdx.x * 256 + threadIdx.x) * 8;
    const float4 a = *(const float4*)(X + i);
    const float4 b = *(const float4*)(X + i + 4);
    u16 h[8] = { f2bf(a.x), f2bf(a.y), f2bf(a.z), f2bf(a.w),
                 f2bf(b.x), f2bf(b.y), f2bf(b.z), f2bf(b.w) };
    *(uint4*)(Xb + i) = *(uint4*)h;
}

// ---------------------------------------------------------------------------
// Transpose+convert: W[K][N] fp32 -> WT[N][K] bf16. 64x64 tiles.
// ---------------------------------------------------------------------------
__global__ __launch_bounds__(256)
void transpose_w(const float* __restrict__ W, u16* __restrict__ WT, int K, int N)
{
    __shared__ float tile[64][65];
    const int n0 = blockIdx.x * 64, k0 = blockIdx.y * 64;
    const int t = threadIdx.x;
    #pragma unroll
    for (int i = 0; i < 4; ++i) {
        const int idx = i*256 + t;
        const int row = idx >> 4, c4 = (idx & 15) * 4;
        const float4 v = *(const float4*)(W + (size_t)(k0 + row)*N + n0 + c4);
        tile[row][c4+0] = v.x; tile[row][c4+1] = v.y;
        tile[row][c4+2] = v.z; tile[row][c4+3] = v.w;
    }
    __syncthreads();
    #pragma unroll
    for (int j = 0; j < 2; ++j) {
        const int idx = j*256 + t;
        const int nr = idx >> 3, kc = (idx & 7) * 8;
        u16 h[8];
        #pragma unroll
        for (int e = 0; e < 8; ++e) h[e] = f2bf(tile[kc + e][nr]);
        *(uint4*)(WT + (size_t)(n0 + nr)*K + k0 + kc) = *(uint4*)h;
    }
}

// ---------------------------------------------------------------------------
// 128x128 bf16 MFMA GEMM, BK=32. 256 threads, 4 waves (64x64 out, 4x4 frags),
// 3-stage LDS pipeline, counted s_waitcnt vmcnt(4) + raw s_barrier; final
// step drains vmcnt(0). L2-aware XCD mapping: per-XCD chunk covers only
// nx/8 B-panels (B working set fits the 4MB per-XCD L2; A-panel uses are
// back-to-back). Epilogue: branch hoisted per (i,j); V^T stores ushort4.
// LDS XOR-swizzle (chunk ^= (row>>1)&3), pre-swizzled global source.
// ---------------------------------------------------------------------------
template<int EPI>
__global__ __launch_bounds__(256, 3)
void gemm128(const u16* __restrict__ A, const u16* __restrict__ Bt,
             const float* __restrict__ bias, float* __restrict__ Cf,
             u16* __restrict__ Qo, u16* __restrict__ Ko, u16* __restrict__ Vo,
             int M, int N, int K)
{
    __shared__ u16 As[3][128][32];
    __shared__ u16 Bs[3][128][32];

    const int nx  = N >> 7;                   // 24 (QKV) or 8 (proj), % 8 == 0
    const int q   = nx >> 3;                  // B-panels per XCD chunk
    const int xcd = blockIdx.x & 7;
    const int c   = blockIdx.x >> 3;          // chunk-local index
    const int tN  = xcd * q + (q > 1 ? (c % q) : 0);
    const int tM  = (q > 1 ? (c / q) : c);

    const int t = threadIdx.x, l = t & 63, w = t >> 6;
    const int wm = w >> 1, wn = w & 1;
    const int lrow = l & 15, lk = l >> 4;

    f32x4 acc[4][4] = {};

    const u16* Ag = A  + (size_t)tM * 128 * K;
    const u16* Bg = Bt + (size_t)tN * 128 * K;

    int srow[2], sch[2];
    #pragma unroll
    for (int r = 0; r < 2; ++r) {
        const int cc = r*256 + t;
        srow[r] = cc >> 2;
        sch[r]  = (cc & 3) ^ ((srow[r] >> 1) & 3);
    }
    const size_t ldso = (size_t)(t & 192) * 8;

    #define STAGE(buf, ks)                                                      \
        {                                                                       \
            _Pragma("unroll")                                                   \
            for (int r = 0; r < 2; ++r) {                                       \
                gll16(Ag + (size_t)srow[r]*K + (ks) + sch[r]*8,                 \
                      &As[buf][0][0] + (size_t)r*2048 + ldso);                  \
                gll16(Bg + (size_t)srow[r]*K + (ks) + sch[r]*8,                 \
                      &Bs[buf][0][0] + (size_t)r*2048 + ldso);                  \
            }                                                                   \
        }

    STAGE(0, 0);
    STAGE(1, 32);

    const int nk = K >> 5;                    // 32
    int cur = 0;
    for (int i = 0; i < nk; ++i) {
        if (i + 1 < nk) { asm volatile("s_waitcnt vmcnt(4)" ::: "memory"); }
        else            { asm volatile("s_waitcnt vmcnt(0)" ::: "memory"); }
        __builtin_amdgcn_sched_barrier(0);
        __builtin_amdgcn_s_barrier();

        bf16x8 a[4], bb[4];
        #pragma unroll
        for (int ii = 0; ii < 4; ++ii) {
            const int ar = wm*64 + ii*16 + lrow;
            a[ii] = ld_bf8(&As[cur][ar][(lk ^ ((ar >> 1) & 3)) * 8]);
        }
        #pragma unroll
        for (int j = 0; j < 4; ++j) {
            const int br = wn*64 + j*16 + lrow;
            bb[j] = ld_bf8(&Bs[cur][br][(lk ^ ((br >> 1) & 3)) * 8]);
        }

        if (i + 2 < nk) {
            const int nb = (cur + 2) - ((cur + 2) >= 3 ? 3 : 0);
            STAGE(nb, (i + 2) * 32);
        }

        __builtin_amdgcn_s_setprio(1);
        #pragma unroll
        for (int ii = 0; ii < 4; ++ii)
        #pragma unroll
        for (int j = 0; j < 4; ++j)
            acc[ii][j] = __builtin_amdgcn_mfma_f32_16x16x32_bf16(a[ii], bb[j], acc[ii][j], 0, 0, 0);
        __builtin_amdgcn_s_setprio(0);

        cur = (cur + 1) - ((cur + 1) >= 3 ? 3 : 0);
    }
    #undef STAGE

    #pragma unroll
    for (int i = 0; i < 4; ++i)
    #pragma unroll
    for (int j = 0; j < 4; ++j) {
        const int row0 = tM*128 + wm*64 + i*16 + lk*4;
        const int col  = tN*128 + wn*64 + j*16 + lrow;
        const float bv = bias[col];
        if (EPI == 0) {
            #pragma unroll
            for (int r = 0; r < 4; ++r)
                Cf[(size_t)(row0 + r) * N + col] = acc[i][j][r] + bv;
        } else {
            const int which = col >> 10;
            const int h  = (col & 1023) >> 6;
            const int hd = col & 63;
            if (which == 2) {
                const int b  = row0 >> 11;
                const int tt = row0 & 2047;
                const int bh = b * Hsz + h;
                u16 pk[4] = { f2bf(acc[i][j][0] + bv), f2bf(acc[i][j][1] + bv),
                              f2bf(acc[i][j][2] + bv), f2bf(acc[i][j][3] + bv) };
                *(ushort4*)(Vo + ((size_t)bh * HDsz + hd) * Tsz + tt) = *(ushort4*)pk;
            } else {
                u16* P = (which == 0) ? Qo : Ko;
                #pragma unroll
                for (int r = 0; r < 4; ++r) {
                    const int row = row0 + r;
                    const int bh  = (row >> 11) * Hsz + h;
                    P[((size_t)bh * Tsz + (row & 2047)) * HDsz + hd] =
                        f2bf(acc[i][j][r] + bv);
                }
            }
        }
    }
}

// ---------------------------------------------------------------------------
// Flash attention v4 (causal) — R6/R11/R14/R16's proven kernel. 4 waves x 32
// q-rows; KVBLK=64, double-buffered; P in registers (16x16x16 PV);
// defer-max; per-CU balanced qt swizzle; tree max + parallel partial sums.
// __expf softmax (R17 showed exp2f lowers through a slower libm path).
// ---------------------------------------------------------------------------
__global__ __launch_bounds__(256, 4)
void attn3(const u16* __restrict__ Q, const u16* __restrict__ K,
           const u16* __restrict__ Vt, u16* __restrict__ AO)
{
    __shared__ u16 KV[2][2][64][64];   // [buf][K/V][row][col], 32 KB

    const int y = blockIdx.y;                       // bh
    const int x = blockIdx.x;                       // 0..15
    const int idx = (x + (y >> 4)) & 15;
    const int qt = (idx & 1) ? (idx >> 1) : (15 - (idx >> 1));
    const int bh = y;
    const int t = threadIdx.x, w = t >> 6, l = t & 63;
    const int lrow = l & 15, lk = l >> 4;
    const int qw = qt*128 + w*32;
    const int qwmax = qw + 31;
    const int swz = lrow & 7;

    const u16* Qh = Q  + (size_t)bh * Tsz * HDsz;
    const u16* Kh = K  + (size_t)bh * Tsz * HDsz;
    const u16* Vh = Vt + (size_t)bh * HDsz * Tsz;

    bf16x8 qf[2][2];
    #pragma unroll
    for (int f = 0; f < 2; ++f)
    #pragma unroll
    for (int kh = 0; kh < 2; ++kh)
        qf[f][kh] = ld_bf8(&Qh[(size_t)(qw + f*16 + lrow)*HDsz + kh*32 + lk*8]);

    f32x4 o[2][4] = {};
    float m[2] = {-3e38f, -3e38f}, lsum[2] = {0.f, 0.f};

    const int ntile = 2*qt + 2;
    int cur = 0;

    #pragma unroll
    for (int rr = 0; rr < 2; ++rr) {
        const int c = rr*256 + t;
        const int row = c >> 3, gc = (c & 7) ^ (row & 7);
        gll16(Kh + (size_t)row*HDsz + gc*8,
              &KV[0][0][0][0] + (size_t)(rr*256 + (t & 192))*8);
        gll16(Vh + (size_t)row*Tsz + gc*8,
              &KV[0][1][0][0] + (size_t)(rr*256 + (t & 192))*8);
    }
    __syncthreads();

    for (int tk = 0; tk < ntile; ++tk) {
        if (tk + 1 < ntile) {
            const int nkv = (tk + 1) * 64;
            #pragma unroll
            for (int rr = 0; rr < 2; ++rr) {
                const int c = rr*256 + t;
                const int row = c >> 3, gc = (c & 7) ^ (row & 7);
                gll16(Kh + (size_t)(nkv + row)*HDsz + gc*8,
                      &KV[cur^1][0][0][0] + (size_t)(rr*256 + (t & 192))*8);
                gll16(Vh + (size_t)row*Tsz + nkv + gc*8,
                      &KV[cur^1][1][0][0] + (size_t)(rr*256 + (t & 192))*8);
            }
        }
        const int kv0 = tk * 64;
        if (kv0 <= qwmax) {
            const u16 (*Ks)[64] = KV[cur][0];
            const u16 (*Vs)[64] = KV[cur][1];
            const bool fullc    = (kv0 + 63 <= qwmax);
            const bool needmask = (kv0 + 63 > qw);

            f32x4 s[2][4];
            __builtin_amdgcn_s_setprio(1);
            #pragma unroll
            for (int c = 0; c < 4; ++c) {
                if (c >= 2 && !fullc) continue;
                const bf16x8 k0 = ld_bf8(&Ks[c*16 + lrow][((0 + lk) ^ swz) * 8]);
                const bf16x8 k1 = ld_bf8(&Ks[c*16 + lrow][((4 + lk) ^ swz) * 8]);
                #pragma unroll
                for (int f = 0; f < 2; ++f) {
                    f32x4 z = {};
                    z = __builtin_amdgcn_mfma_f32_16x16x32_bf16(k0, qf[f][0], z, 0, 0, 0);
                    z = __builtin_amdgcn_mfma_f32_16x16x32_bf16(k1, qf[f][1], z, 0, 0, 0);
                    s[f][c] = z;
                }
            }
            __builtin_amdgcn_s_setprio(0);

            #pragma unroll
            for (int f = 0; f < 2; ++f) {
                const int q = qw + f*16 + lrow;
                if (needmask) {
                    #pragma unroll
                    for (int c = 0; c < 4; ++c) {
                        if (c >= 2 && !fullc) continue;
                        const int base = kv0 + c*16 + lk*4;
                        #pragma unroll
                        for (int r = 0; r < 4; ++r)
                            if (base + r > q) s[f][c][r] = -1e30f;
                    }
                }
                f32x4 t01;
                #pragma unroll
                for (int r = 0; r < 4; ++r) {
                    t01[r] = fmaxf(s[f][0][r], s[f][1][r]);
                    if (fullc) t01[r] = fmaxf(t01[r], fmaxf(s[f][2][r], s[f][3][r]));
                }
                float mx = fmaxf(fmaxf(t01[0], t01[1]), fmaxf(t01[2], t01[3]));
                mx = fmaxf(mx, __shfl_xor(mx, 16));
                mx = fmaxf(mx, __shfl_xor(mx, 32));
                if (__any(mx > m[f] + 64.f)) {          // defer-max (THR=8 scaled)
                    const float mn = fmaxf(m[f], mx);
                    const float al = __expf((m[f] - mn) * 0.125f);
                    lsum[f] *= al;
                    m[f] = mn;
                    #pragma unroll
                    for (int c = 0; c < 4; ++c)
                    #pragma unroll
                    for (int r = 0; r < 4; ++r) o[f][c][r] *= al;
                }
                const float nm8 = -m[f] * 0.125f;
                f32x4 ps4 = {};
                #pragma unroll
                for (int c = 0; c < 4; ++c) {
                    if (c >= 2 && !fullc) continue;
                    #pragma unroll
                    for (int r = 0; r < 4; ++r) {
                        const float p = __expf(fmaf(s[f][c][r], 0.125f, nm8));
                        s[f][c][r] = p;
                        ps4[r] += p;
                    }
                }
                float ps = (ps4[0] + ps4[1]) + (ps4[2] + ps4[3]);
                ps += __shfl_xor(ps, 16);
                ps += __shfl_xor(ps, 32);
                lsum[f] += ps;
            }

            __builtin_amdgcn_s_setprio(1);
            #pragma unroll
            for (int c = 0; c < 4; ++c) {
                if (c >= 2 && !fullc) continue;
                union { bf16x4 v; f32x2 f; } p0, p1;
                #pragma unroll
                for (int r = 0; r < 4; ++r) {
                    p0.v[r] = (__bf16)s[0][c][r];
                    p1.v[r] = (__bf16)s[1][c][r];
                }
                #pragma unroll
                for (int chd = 0; chd < 4; ++chd) {
                    const f32x2 va = *reinterpret_cast<const f32x2*>(
                        &Vs[chd*16 + lrow][(((c*2 + (lk >> 1)) ^ swz) << 3) + ((lk & 1) << 2)]);
                    mfma16(o[0][chd], va, p0.f);
                    mfma16(o[1][chd], va, p1.f);
                }
            }
            __builtin_amdgcn_s_setprio(0);
        }
        __syncthreads();
        cur ^= 1;
    }

    const int b = bh >> 4, h = bh & 15;
    #pragma unroll
    for (int f = 0; f < 2; ++f) {
        const float rl = 1.0f / lsum[f];
        #pragma unroll
        for (int chd = 0; chd < 4; ++chd) {
            u16 ov[4] = { f2bf(o[f][chd][0]*rl), f2bf(o[f][chd][1]*rl),
                          f2bf(o[f][chd][2]*rl), f2bf(o[f][chd][3]*rl) };
            *(ushort4*)(AO + ((size_t)(b*Tsz + qw + f*16 + lrow))*Dsz
                           + h*HDsz + chd*16 + lk*4) = *(ushort4*)ov;
        }
    }
}

extern "C" void kernel_launch(void* const* d_in, const int* in_sizes, int n_in,
                              void* d_out, int out_size, void* d_ws, size_t ws_size,
                              hipStream_t stream)
{
    (void)in_sizes; (void)n_in; (void)out_size; (void)ws_size;

    const float* x      = (const float*)d_in[0];
    const float* qkv_w  = (const float*)d_in[1];
    const float* qkv_b  = (const float*)d_in[2];
    const float* proj_w = (const float*)d_in[3];
    const float* proj_b = (const float*)d_in[4];
    float* out = (float*)d_out;

    char* ws = (char*)d_ws;
    const size_t SZ = (size_t)Bsz * Hsz * Tsz * HDsz * sizeof(u16);  // 16 MB
    u16* R0 = (u16*)(ws);
    u16* Qb = (u16*)(ws + SZ);
    u16* Kb = (u16*)(ws + 2*SZ);
    u16* Vt = (u16*)(ws + 3*SZ);
    u16* WQKVT = R0;          // dead after QKV GEMM
    u16* AO    = R0;          // reuses WQKVT region
    u16* WPT   = Qb;          // reuses Q region after attention

    // x as bf16, staged in d_out's first 16.8 MB (out is 33.5 MB fp32,
    // fully overwritten by the proj GEMM at the end -> safe scratch).
    u16* Xb = (u16*)d_out;

    const int M = Bsz * Tsz;  // 8192

    conv_bf16<<<(M*Dsz)/(256*8), 256, 0, stream>>>(x, Xb);
    transpose_w<<<dim3(3*Dsz/64, Dsz/64), 256, 0, stream>>>(qkv_w, WQKVT, Dsz, 3*Dsz);
    gemm128<1><<<dim3((3*Dsz/128) * (M/128)), 256, 0, stream>>>(
        Xb, WQKVT, qkv_b, nullptr, Qb, Kb, Vt, M, 3*Dsz, Dsz);
    attn3<<<dim3(Tsz/128, Bsz*Hsz), 256, 0, stream>>>(Qb, Kb, Vt, AO);
    transpose_w<<<dim3(Dsz/64, Dsz/64), 256, 0, stream>>>(proj_w, WPT, Dsz, Dsz);
    gemm128<0><<<dim3((Dsz/128) * (M/128)), 256, 0, stream>>>(
        AO, WPT, proj_b, out, nullptr, nullptr, nullptr, M, Dsz, Dsz);
}

// Round 19
// 193.672 us; speedup vs baseline: 1.0753x; 1.0045x over previous
//
#include <hip/hip_runtime.h>
#include <hip/hip_bf16.h>

// B=4, T=2048, D=1024, H=16, HD=64
#define Bsz 4
#define Tsz 2048
#define Dsz 1024
#define Hsz 16
#define HDsz 64

typedef __attribute__((ext_vector_type(8))) __bf16 bf16x8;
typedef __attribute__((ext_vector_type(4))) __bf16 bf16x4;
typedef __attribute__((ext_vector_type(4))) float f32x4;
typedef __attribute__((ext_vector_type(2))) float f32x2;
typedef unsigned short u16;
typedef unsigned int u32;

#define DEVI static __device__ __forceinline__

DEVI u16 f2bf(float f) {
    __bf16 h = (__bf16)f;
    union { __bf16 h; u16 u; } c; c.h = h; return c.u;
}
DEVI bf16x8 ld_bf8(const u16* p) { return *reinterpret_cast<const bf16x8*>(p); }

// async global->LDS, 16B per lane. lds dest is wave-uniform base + lane*16.
DEVI void gll16(const u16* g, u16* lds) {
    __builtin_amdgcn_global_load_lds(
        (const __attribute__((address_space(1))) u32*)g,
        (__attribute__((address_space(3))) u32*)lds, 16, 0, 0);
}

// K=16 MFMA: acc(16x16, f32) += A(16x16 bf16) * B(16x16 bf16).
DEVI void mfma16(f32x4& c, f32x2 a, f32x2 b) {
    asm("v_mfma_f32_16x16x16_bf16 %0, %1, %2, %0" : "+v"(c) : "v"(a), "v"(b));
}

// ---------------------------------------------------------------------------
// fp32 -> bf16 bulk convert (8 elems/thread, single pass)
// ---------------------------------------------------------------------------
__global__ __launch_bounds__(256)
void conv_bf16(const float* __restrict__ X, u16* __restrict__ Xb)
{
    const size_t i = ((size_t)blockIdx.x * 256 + threadIdx.x) * 8;
    const float4 a = *(const float4*)(X + i);
    const float4 b = *(const float4*)(X + i + 4);
    u16 h[8] = { f2bf(a.x), f2bf(a.y), f2bf(a.z), f2bf(a.w),
                 f2bf(b.x), f2bf(b.y), f2bf(b.z), f2bf(b.w) };
    *(uint4*)(Xb + i) = *(uint4*)h;
}

// ---------------------------------------------------------------------------
// Transpose+convert: W[K][N] fp32 -> WT[N][K] bf16. 64x64 tiles.
// ---------------------------------------------------------------------------
__global__ __launch_bounds__(256)
void transpose_w(const float* __restrict__ W, u16* __restrict__ WT, int K, int N)
{
    __shared__ float tile[64][65];
    const int n0 = blockIdx.x * 64, k0 = blockIdx.y * 64;
    const int t = threadIdx.x;
    #pragma unroll
    for (int i = 0; i < 4; ++i) {
        const int idx = i*256 + t;
        const int row = idx >> 4, c4 = (idx & 15) * 4;
        const float4 v = *(const float4*)(W + (size_t)(k0 + row)*N + n0 + c4);
        tile[row][c4+0] = v.x; tile[row][c4+1] = v.y;
        tile[row][c4+2] = v.z; tile[row][c4+3] = v.w;
    }
    __syncthreads();
    #pragma unroll
    for (int j = 0; j < 2; ++j) {
        const int idx = j*256 + t;
        const int nr = idx >> 3, kc = (idx & 7) * 8;
        u16 h[8];
        #pragma unroll
        for (int e = 0; e < 8; ++e) h[e] = f2bf(tile[kc + e][nr]);
        *(uint4*)(WT + (size_t)(n0 + nr)*K + k0 + kc) = *(uint4*)h;
    }
}

// ---------------------------------------------------------------------------
// 128x128 bf16 MFMA GEMM, BK=32. 256 threads, 4 waves (64x64 out, 4x4 frags),
// 3-stage LDS pipeline, counted s_waitcnt vmcnt(4) + raw s_barrier; final
// step drains vmcnt(0). L2-aware XCD mapping: per-XCD chunk covers only
// nx/8 B-panels (B working set fits the 4MB per-XCD L2; A-panel uses are
// back-to-back). Epilogue: branch hoisted per (i,j); V^T stores ushort4.
// LDS XOR-swizzle (chunk ^= (row>>1)&3), pre-swizzled global source.
// ---------------------------------------------------------------------------
template<int EPI>
__global__ __launch_bounds__(256, 3)
void gemm128(const u16* __restrict__ A, const u16* __restrict__ Bt,
             const float* __restrict__ bias, float* __restrict__ Cf,
             u16* __restrict__ Qo, u16* __restrict__ Ko, u16* __restrict__ Vo,
             int M, int N, int K)
{
    __shared__ u16 As[3][128][32];
    __shared__ u16 Bs[3][128][32];

    const int nx  = N >> 7;                   // 24 (QKV) or 8 (proj), % 8 == 0
    const int q   = nx >> 3;                  // B-panels per XCD chunk
    const int xcd = blockIdx.x & 7;
    const int c   = blockIdx.x >> 3;          // chunk-local index
    const int tN  = xcd * q + (q > 1 ? (c % q) : 0);
    const int tM  = (q > 1 ? (c / q) : c);

    const int t = threadIdx.x, l = t & 63, w = t >> 6;
    const int wm = w >> 1, wn = w & 1;
    const int lrow = l & 15, lk = l >> 4;

    f32x4 acc[4][4] = {};

    const u16* Ag = A  + (size_t)tM * 128 * K;
    const u16* Bg = Bt + (size_t)tN * 128 * K;

    int srow[2], sch[2];
    #pragma unroll
    for (int r = 0; r < 2; ++r) {
        const int cc = r*256 + t;
        srow[r] = cc >> 2;
        sch[r]  = (cc & 3) ^ ((srow[r] >> 1) & 3);
    }
    const size_t ldso = (size_t)(t & 192) * 8;

    #define STAGE(buf, ks)                                                      \
        {                                                                       \
            _Pragma("unroll")                                                   \
            for (int r = 0; r < 2; ++r) {                                       \
                gll16(Ag + (size_t)srow[r]*K + (ks) + sch[r]*8,                 \
                      &As[buf][0][0] + (size_t)r*2048 + ldso);                  \
                gll16(Bg + (size_t)srow[r]*K + (ks) + sch[r]*8,                 \
                      &Bs[buf][0][0] + (size_t)r*2048 + ldso);                  \
            }                                                                   \
        }

    STAGE(0, 0);
    STAGE(1, 32);

    const int nk = K >> 5;                    // 32
    int cur = 0;
    for (int i = 0; i < nk; ++i) {
        if (i + 1 < nk) { asm volatile("s_waitcnt vmcnt(4)" ::: "memory"); }
        else            { asm volatile("s_waitcnt vmcnt(0)" ::: "memory"); }
        __builtin_amdgcn_sched_barrier(0);
        __builtin_amdgcn_s_barrier();

        bf16x8 a[4], bb[4];
        #pragma unroll
        for (int ii = 0; ii < 4; ++ii) {
            const int ar = wm*64 + ii*16 + lrow;
            a[ii] = ld_bf8(&As[cur][ar][(lk ^ ((ar >> 1) & 3)) * 8]);
        }
        #pragma unroll
        for (int j = 0; j < 4; ++j) {
            const int br = wn*64 + j*16 + lrow;
            bb[j] = ld_bf8(&Bs[cur][br][(lk ^ ((br >> 1) & 3)) * 8]);
        }

        if (i + 2 < nk) {
            const int nb = (cur + 2) - ((cur + 2) >= 3 ? 3 : 0);
            STAGE(nb, (i + 2) * 32);
        }

        __builtin_amdgcn_s_setprio(1);
        #pragma unroll
        for (int ii = 0; ii < 4; ++ii)
        #pragma unroll
        for (int j = 0; j < 4; ++j)
            acc[ii][j] = __builtin_amdgcn_mfma_f32_16x16x32_bf16(a[ii], bb[j], acc[ii][j], 0, 0, 0);
        __builtin_amdgcn_s_setprio(0);

        cur = (cur + 1) - ((cur + 1) >= 3 ? 3 : 0);
    }
    #undef STAGE

    #pragma unroll
    for (int i = 0; i < 4; ++i)
    #pragma unroll
    for (int j = 0; j < 4; ++j) {
        const int row0 = tM*128 + wm*64 + i*16 + lk*4;
        const int col  = tN*128 + wn*64 + j*16 + lrow;
        const float bv = bias[col];
        if (EPI == 0) {
            #pragma unroll
            for (int r = 0; r < 4; ++r)
                Cf[(size_t)(row0 + r) * N + col] = acc[i][j][r] + bv;
        } else {
            const int which = col >> 10;
            const int h  = (col & 1023) >> 6;
            const int hd = col & 63;
            if (which == 2) {
                const int b  = row0 >> 11;
                const int tt = row0 & 2047;
                const int bh = b * Hsz + h;
                u16 pk[4] = { f2bf(acc[i][j][0] + bv), f2bf(acc[i][j][1] + bv),
                              f2bf(acc[i][j][2] + bv), f2bf(acc[i][j][3] + bv) };
                *(ushort4*)(Vo + ((size_t)bh * HDsz + hd) * Tsz + tt) = *(ushort4*)pk;
            } else {
                u16* P = (which == 0) ? Qo : Ko;
                #pragma unroll
                for (int r = 0; r < 4; ++r) {
                    const int row = row0 + r;
                    const int bh  = (row >> 11) * Hsz + h;
                    P[((size_t)bh * Tsz + (row & 2047)) * HDsz + hd] =
                        f2bf(acc[i][j][r] + bv);
                }
            }
        }
    }
}

// ---------------------------------------------------------------------------
// Flash attention v4.2 (causal) — proven R14/R16/R18 body; ONLY change is the
// block->(qt,bh) mapping: bh-per-XCD grouping. With dispatch XCD = lin mod 8,
// map r = lin&7 -> bh = r + 8*((lin>>3)>>4), so all 16 q-tile blocks of a bh
// run on ONE XCD: its K/V stream (0.5 MB/bh, 8 bh/XCD = 4 MB) becomes
// L2-resident, and the double-buffer prefetch completes under compute
// (L2-hit ~200cy instead of HBM ~900cy). Per-CU balance preserved: a CU's 4
// blocks (lin stride 256) have g stepping by 2 -> qidx consecutive -> the
// balanced perm gives 2 heavy + 2 light per CU (same property as R11).
// Bijective over (qt,bh) by construction.
// ---------------------------------------------------------------------------
__global__ __launch_bounds__(256, 4)
void attn3(const u16* __restrict__ Q, const u16* __restrict__ K,
           const u16* __restrict__ Vt, u16* __restrict__ AO)
{
    __shared__ u16 KV[2][2][64][64];   // [buf][K/V][row][col], 32 KB

    const int lin = (int)blockIdx.y * 16 + (int)blockIdx.x;   // 0..1023
    const int r   = lin & 7;                                  // XCD slot
    const int k   = lin >> 3;                                 // 0..127
    const int g   = k >> 4;                                   // 0..7
    const int bh  = r + 8 * g;                                // bh-per-XCD
    const int qidx = ((k & 15) + (g >> 1)) & 15;
    const int qt  = (qidx & 1) ? (qidx >> 1) : (15 - (qidx >> 1));
    const int t = threadIdx.x, w = t >> 6, l = t & 63;
    const int lrow = l & 15, lk = l >> 4;
    const int qw = qt*128 + w*32;
    const int qwmax = qw + 31;
    const int swz = lrow & 7;

    const u16* Qh = Q  + (size_t)bh * Tsz * HDsz;
    const u16* Kh = K  + (size_t)bh * Tsz * HDsz;
    const u16* Vh = Vt + (size_t)bh * HDsz * Tsz;

    bf16x8 qf[2][2];
    #pragma unroll
    for (int f = 0; f < 2; ++f)
    #pragma unroll
    for (int kh = 0; kh < 2; ++kh)
        qf[f][kh] = ld_bf8(&Qh[(size_t)(qw + f*16 + lrow)*HDsz + kh*32 + lk*8]);

    f32x4 o[2][4] = {};
    float m[2] = {-3e38f, -3e38f}, lsum[2] = {0.f, 0.f};

    const int ntile = 2*qt + 2;
    int cur = 0;

    #pragma unroll
    for (int rr = 0; rr < 2; ++rr) {
        const int c = rr*256 + t;
        const int row = c >> 3, gc = (c & 7) ^ (row & 7);
        gll16(Kh + (size_t)row*HDsz + gc*8,
              &KV[0][0][0][0] + (size_t)(rr*256 + (t & 192))*8);
        gll16(Vh + (size_t)row*Tsz + gc*8,
              &KV[0][1][0][0] + (size_t)(rr*256 + (t & 192))*8);
    }
    __syncthreads();

    for (int tk = 0; tk < ntile; ++tk) {
        if (tk + 1 < ntile) {
            const int nkv = (tk + 1) * 64;
            #pragma unroll
            for (int rr = 0; rr < 2; ++rr) {
                const int c = rr*256 + t;
                const int row = c >> 3, gc = (c & 7) ^ (row & 7);
                gll16(Kh + (size_t)(nkv + row)*HDsz + gc*8,
                      &KV[cur^1][0][0][0] + (size_t)(rr*256 + (t & 192))*8);
                gll16(Vh + (size_t)row*Tsz + nkv + gc*8,
                      &KV[cur^1][1][0][0] + (size_t)(rr*256 + (t & 192))*8);
            }
        }
        const int kv0 = tk * 64;
        if (kv0 <= qwmax) {
            const u16 (*Ks)[64] = KV[cur][0];
            const u16 (*Vs)[64] = KV[cur][1];
            const bool fullc    = (kv0 + 63 <= qwmax);
            const bool needmask = (kv0 + 63 > qw);

            f32x4 s[2][4];
            __builtin_amdgcn_s_setprio(1);
            #pragma unroll
            for (int c = 0; c < 4; ++c) {
                if (c >= 2 && !fullc) continue;
                const bf16x8 k0 = ld_bf8(&Ks[c*16 + lrow][((0 + lk) ^ swz) * 8]);
                const bf16x8 k1 = ld_bf8(&Ks[c*16 + lrow][((4 + lk) ^ swz) * 8]);
                #pragma unroll
                for (int f = 0; f < 2; ++f) {
                    f32x4 z = {};
                    z = __builtin_amdgcn_mfma_f32_16x16x32_bf16(k0, qf[f][0], z, 0, 0, 0);
                    z = __builtin_amdgcn_mfma_f32_16x16x32_bf16(k1, qf[f][1], z, 0, 0, 0);
                    s[f][c] = z;
                }
            }
            __builtin_amdgcn_s_setprio(0);

            #pragma unroll
            for (int f = 0; f < 2; ++f) {
                const int q = qw + f*16 + lrow;
                if (needmask) {
                    #pragma unroll
                    for (int c = 0; c < 4; ++c) {
                        if (c >= 2 && !fullc) continue;
                        const int base = kv0 + c*16 + lk*4;
                        #pragma unroll
                        for (int r2 = 0; r2 < 4; ++r2)
                            if (base + r2 > q) s[f][c][r2] = -1e30f;
                    }
                }
                f32x4 t01;
                #pragma unroll
                for (int r2 = 0; r2 < 4; ++r2) {
                    t01[r2] = fmaxf(s[f][0][r2], s[f][1][r2]);
                    if (fullc) t01[r2] = fmaxf(t01[r2], fmaxf(s[f][2][r2], s[f][3][r2]));
                }
                float mx = fmaxf(fmaxf(t01[0], t01[1]), fmaxf(t01[2], t01[3]));
                mx = fmaxf(mx, __shfl_xor(mx, 16));
                mx = fmaxf(mx, __shfl_xor(mx, 32));
                if (__any(mx > m[f] + 64.f)) {          // defer-max (THR=8 scaled)
                    const float mn = fmaxf(m[f], mx);
                    const float al = __expf((m[f] - mn) * 0.125f);
                    lsum[f] *= al;
                    m[f] = mn;
                    #pragma unroll
                    for (int c = 0; c < 4; ++c)
                    #pragma unroll
                    for (int r2 = 0; r2 < 4; ++r2) o[f][c][r2] *= al;
                }
                const float nm8 = -m[f] * 0.125f;
                f32x4 ps4 = {};
                #pragma unroll
                for (int c = 0; c < 4; ++c) {
                    if (c >= 2 && !fullc) continue;
                    #pragma unroll
                    for (int r2 = 0; r2 < 4; ++r2) {
                        const float p = __expf(fmaf(s[f][c][r2], 0.125f, nm8));
                        s[f][c][r2] = p;
                        ps4[r2] += p;
                    }
                }
                float ps = (ps4[0] + ps4[1]) + (ps4[2] + ps4[3]);
                ps += __shfl_xor(ps, 16);
                ps += __shfl_xor(ps, 32);
                lsum[f] += ps;
            }

            __builtin_amdgcn_s_setprio(1);
            #pragma unroll
            for (int c = 0; c < 4; ++c) {
                if (c >= 2 && !fullc) continue;
                union { bf16x4 v; f32x2 f; } p0, p1;
                #pragma unroll
                for (int r2 = 0; r2 < 4; ++r2) {
                    p0.v[r2] = (__bf16)s[0][c][r2];
                    p1.v[r2] = (__bf16)s[1][c][r2];
                }
                #pragma unroll
                for (int chd = 0; chd < 4; ++chd) {
                    const f32x2 va = *reinterpret_cast<const f32x2*>(
                        &Vs[chd*16 + lrow][(((c*2 + (lk >> 1)) ^ swz) << 3) + ((lk & 1) << 2)]);
                    mfma16(o[0][chd], va, p0.f);
                    mfma16(o[1][chd], va, p1.f);
                }
            }
            __builtin_amdgcn_s_setprio(0);
        }
        __syncthreads();
        cur ^= 1;
    }

    const int b = bh >> 4, h = bh & 15;
    #pragma unroll
    for (int f = 0; f < 2; ++f) {
        const float rl = 1.0f / lsum[f];
        #pragma unroll
        for (int chd = 0; chd < 4; ++chd) {
            u16 ov[4] = { f2bf(o[f][chd][0]*rl), f2bf(o[f][chd][1]*rl),
                          f2bf(o[f][chd][2]*rl), f2bf(o[f][chd][3]*rl) };
            *(ushort4*)(AO + ((size_t)(b*Tsz + qw + f*16 + lrow))*Dsz
                           + h*HDsz + chd*16 + lk*4) = *(ushort4*)ov;
        }
    }
}

extern "C" void kernel_launch(void* const* d_in, const int* in_sizes, int n_in,
                              void* d_out, int out_size, void* d_ws, size_t ws_size,
                              hipStream_t stream)
{
    (void)in_sizes; (void)n_in; (void)out_size; (void)ws_size;

    const float* x      = (const float*)d_in[0];
    const float* qkv_w  = (const float*)d_in[1];
    const float* qkv_b  = (const float*)d_in[2];
    const float* proj_w = (const float*)d_in[3];
    const float* proj_b = (const float*)d_in[4];
    float* out = (float*)d_out;

    char* ws = (char*)d_ws;
    const size_t SZ = (size_t)Bsz * Hsz * Tsz * HDsz * sizeof(u16);  // 16 MB
    u16* R0 = (u16*)(ws);
    u16* Qb = (u16*)(ws + SZ);
    u16* Kb = (u16*)(ws + 2*SZ);
    u16* Vt = (u16*)(ws + 3*SZ);
    u16* WQKVT = R0;          // dead after QKV GEMM
    u16* AO    = R0;          // reuses WQKVT region
    u16* WPT   = Qb;          // reuses Q region after attention

    // x as bf16, staged in d_out's first 16.8 MB (out is 33.5 MB fp32,
    // fully overwritten by the proj GEMM at the end -> safe scratch).
    u16* Xb = (u16*)d_out;

    const int M = Bsz * Tsz;  // 8192

    conv_bf16<<<(M*Dsz)/(256*8), 256, 0, stream>>>(x, Xb);
    transpose_w<<<dim3(3*Dsz/64, Dsz/64), 256, 0, stream>>>(qkv_w, WQKVT, Dsz, 3*Dsz);
    gemm128<1><<<dim3((3*Dsz/128) * (M/128)), 256, 0, stream>>>(
        Xb, WQKVT, qkv_b, nullptr, Qb, Kb, Vt, M, 3*Dsz, Dsz);
    attn3<<<dim3(Tsz/128, Bsz*Hsz), 256, 0, stream>>>(Qb, Kb, Vt, AO);
    transpose_w<<<dim3(Dsz/64, Dsz/64), 256, 0, stream>>>(proj_w, WPT, Dsz, Dsz);
    gemm128<0><<<dim3((Dsz/128) * (M/128)), 256, 0, stream>>>(
        AO, WPT, proj_b, out, nullptr, nullptr, nullptr, M, Dsz, Dsz);
}